// Round 2
// baseline (107.597 us; speedup 1.0000x reference)
//
#include <hip/hip_runtime.h>

// Problem dims (fixed by setup_inputs)
#define BS 8
#define NF 16
#define NI 24
#define LL 16384   // 128*128

// Workspace layout (floats)
#define OFF_COUNTS 0                 // [BS][NI]        192
#define OFF_SUMS   192               // [BS][NI][NF]   3072
#define OFF_MEANS  3264              // [BS][NI][NF]   3072
#define OFF_VDEN   6336              // [BS]
#define OFF_DIST   6344              // [BS]
#define OFF_REG    6352              // [BS]
#define OFF_VNUM   6360              // [BS]
#define WS_FLOATS  6368

#define TL 128        // l-tile staged in LDS
#define CHUNKS_A 32   // blocks per batch in k_sums
#define VBLK 32       // blocks per batch in k_var

__device__ __forceinline__ float block_sum(float v, volatile float* red) {
    // wave (64-lane) reduce
    for (int off = 32; off; off >>= 1) v += __shfl_down(v, off);
    __syncthreads();  // protect red[] from any previous use
    if ((threadIdx.x & 63) == 0) red[threadIdx.x >> 6] = v;
    __syncthreads();
    float r = 0.f;
    int nw = blockDim.x >> 6;
    if ((int)threadIdx.x < nw) r = red[threadIdx.x];
    if ((threadIdx.x >> 6) == 0)
        for (int off = 32; off; off >>= 1) r += __shfl_down(r, off);
    return r;  // valid in thread 0
}

// Kernel 1: counts[b,i] and sums[b,i,f] = sum_l gt[b,i,l] * pred[b,l,f]
__global__ __launch_bounds__(384) void k_sums(const float* __restrict__ input,
                                              const int* __restrict__ target,
                                              float* __restrict__ ws) {
    __shared__ float pred_lds[TL][NF + 1];  // +1 pad: conflict-free staged writes
    __shared__ float tgt_lds[NI][TL];
    const int b = blockIdx.y;
    const int t = threadIdx.x;
    const int i = t >> 4;     // 0..23
    const int f = t & 15;     // 0..15
    const float* inb = input + (size_t)b * NF * LL;
    const int*   tgb = target + (size_t)b * NI * LL;

    float acc = 0.f, cnt = 0.f;
    const int l0base = blockIdx.x * (LL / CHUNKS_A);
    for (int tile = 0; tile < (LL / CHUNKS_A) / TL; ++tile) {
        const int l0 = l0base + tile * TL;
        for (int idx = t; idx < NF * TL; idx += 384) {
            int ff = idx >> 7;          // idx / TL
            int j  = idx & (TL - 1);
            pred_lds[j][ff] = inb[ff * LL + l0 + j];
        }
        for (int idx = t; idx < NI * TL; idx += 384) {
            int ii = idx >> 7;
            int j  = idx & (TL - 1);
            tgt_lds[ii][j] = (float)tgb[ii * LL + l0 + j];
        }
        __syncthreads();
        #pragma unroll 8
        for (int j = 0; j < TL; ++j) {
            float tv = tgt_lds[i][j];          // broadcast within 16-lane group
            acc = fmaf(tv, pred_lds[j][f], acc);
            if (f == 0) cnt += tv;
        }
        __syncthreads();
    }
    atomicAdd(&ws[OFF_SUMS + (b * NI + i) * NF + f], acc);
    if (f == 0) atomicAdd(&ws[OFF_COUNTS + b * NI + i], cnt);
}

// Kernel 2: means, var_den, dist term, reg term (one block per batch)
__global__ __launch_bounds__(256) void k_means_dist_reg(const int* __restrict__ n_objects,
                                                        float* __restrict__ ws) {
    const int b = blockIdx.x;
    const int t = threadIdx.x;
    const int n = n_objects[b];
    __shared__ float m_lds[NI][NF];
    __shared__ float red[8];

    for (int idx = t; idx < NI * NF; idx += 256) {
        int i = idx >> 4, f = idx & 15;
        float c = ws[OFF_COUNTS + b * NI + i];
        float s = ws[OFF_SUMS + (b * NI + i) * NF + f];
        float m = (i < n) ? s / (c > 0.f ? c : 1.f) : 0.f;
        m_lds[i][f] = m;
        ws[OFF_MEANS + (b * NI + i) * NF + f] = m;
    }
    __syncthreads();

    float vden = 0.f, reg = 0.f;
    if (t < NI && t < n) {
        vden = ws[OFF_COUNTS + b * NI + t];
        float ss = 0.f;
        #pragma unroll
        for (int f = 0; f < NF; ++f) { float m = m_lds[t][f]; ss += m * m; }
        reg = (ss > 0.f) ? sqrtf(ss) : 0.f;
    }
    float dist = 0.f;
    for (int p = t; p < NI * NI; p += 256) {
        int i = p / NI, j = p % NI;
        if (i != j && i < n && j < n) {
            float ss = 0.f;
            #pragma unroll
            for (int f = 0; f < NF; ++f) { float d = m_lds[i][f] - m_lds[j][f]; ss += d * d; }
            float dn = (ss > 0.f) ? sqrtf(ss) : 0.f;
            float h = fmaxf(3.0f - dn, 0.f);  // margin = 2*DELTA_D = 3 off-diagonal
            dist += h * h;
        }
    }
    float vden_s = block_sum(vden, red);
    float reg_s  = block_sum(reg, red);
    float dist_s = block_sum(dist, red);
    if (t == 0) {
        ws[OFF_VDEN + b] = vden_s;
        ws[OFF_REG + b]  = reg_s / (float)n;
        float nf = (float)n;
        ws[OFF_DIST + b] = (n > 1) ? dist_s / (nf * (nf - 1.f)) : 0.f;
    }
}

// Kernel 3: variance term numerator
__global__ __launch_bounds__(256) void k_var(const float* __restrict__ input,
                                             const int* __restrict__ target,
                                             const int* __restrict__ n_objects,
                                             float* __restrict__ ws) {
    const int b = blockIdx.y;
    const int n = n_objects[b];
    const int t = threadIdx.x;
    __shared__ float m_lds[NI][NF];
    __shared__ float red[8];
    for (int idx = t; idx < NI * NF; idx += 256)
        m_lds[idx >> 4][idx & 15] = ws[OFF_MEANS + b * NI * NF + idx];
    __syncthreads();

    const float* inb = input + (size_t)b * NF * LL;
    const int*   tgb = target + (size_t)b * NI * LL;
    float acc = 0.f;
    for (int l = blockIdx.x * 256 + t; l < LL; l += VBLK * 256) {
        float p[NF];
        #pragma unroll
        for (int f = 0; f < NF; ++f) p[f] = inb[f * LL + l];
        for (int i = 0; i < n; ++i) {
            float tv = (float)tgb[i * LL + l];
            float ss = 0.f;
            #pragma unroll
            for (int f = 0; f < NF; ++f) { float d = p[f] - m_lds[i][f]; ss = fmaf(d, d, ss); }
            float dn = (ss > 0.f) ? sqrtf(ss) : 0.f;
            float h = fmaxf(dn - 0.5f, 0.f);
            acc = fmaf(tv, h * h, acc);
        }
    }
    float s = block_sum(acc, red);
    if (t == 0) atomicAdd(&ws[OFF_VNUM + b], s);
}

// Kernel 4: combine into scalar
__global__ void k_final(const float* __restrict__ ws, float* __restrict__ out) {
    if (threadIdx.x == 0 && blockIdx.x == 0) {
        float vt = 0.f, dt = 0.f, rt = 0.f;
        for (int b = 0; b < BS; ++b) {
            vt += ws[OFF_VNUM + b] / ws[OFF_VDEN + b];
            dt += ws[OFF_DIST + b];
            rt += ws[OFF_REG + b];
        }
        out[0] = (1.0f * vt + 1.0f * dt + 0.001f * rt) * (1.0f / (float)BS);
    }
}

extern "C" void kernel_launch(void* const* d_in, const int* in_sizes, int n_in,
                              void* d_out, int out_size, void* d_ws, size_t ws_size,
                              hipStream_t stream) {
    const float* input     = (const float*)d_in[0];
    const int*   target    = (const int*)d_in[1];
    const int*   n_objects = (const int*)d_in[2];
    float* ws  = (float*)d_ws;
    float* out = (float*)d_out;

    hipMemsetAsync(d_ws, 0, WS_FLOATS * sizeof(float), stream);

    dim3 gA(CHUNKS_A, BS);
    k_sums<<<gA, 384, 0, stream>>>(input, target, ws);
    k_means_dist_reg<<<BS, 256, 0, stream>>>(n_objects, ws);
    dim3 gC(VBLK, BS);
    k_var<<<gC, 256, 0, stream>>>(input, target, n_objects, ws);
    k_final<<<1, 64, 0, stream>>>(ws, out);
}